// Round 1
// baseline (292.415 us; speedup 1.0000x reference)
//
#include <hip/hip_runtime.h>
#include <hip/hip_bf16.h>
#include <stdint.h>

// Problem constants
#define BATCH 256
#define NPOS 49          // 7x7 window
#define CCH 128
#define KWIN 7
#define HEADS 4
#define K2 49
#define HD 32            // CCH / HEADS
#define NCOLS 776        // 384 (qkv) + 392 (off)
#define MROWS (BATCH * NPOS)   // 12544
#define QSCALE 0.17677669529663687f  // 32^-0.5

// ---------------------------------------------------------------------------
// Kernel 0: transpose weights for coalesced GEMM reads.
// wt [128][776]: wt[k*776+col] = (col<384 ? w_qkv[col][k] : w_off[col-384][k])
// wt2[128][128]: wt2[k*128+col] = w_proj[col][k]
// ---------------------------------------------------------------------------
__global__ __launch_bounds__(256) void dwa_transpose_w(
    const float* __restrict__ w_qkv, const float* __restrict__ w_off,
    const float* __restrict__ w_proj, float* __restrict__ wt,
    float* __restrict__ wt2) {
  int i = blockIdx.x * 256 + threadIdx.x;
  const int N1 = 128 * NCOLS;           // 99328
  const int N2 = 128 * 128;             // 16384
  if (i < N1) {
    int k = i / NCOLS;
    int col = i - k * NCOLS;
    float v = (col < 384) ? w_qkv[col * 128 + k] : w_off[(col - 384) * 128 + k];
    wt[i] = v;
  } else if (i < N1 + N2) {
    int j = i - N1;
    int k = j >> 7;
    int col = j & 127;
    wt2[j] = w_proj[col * 128 + k];
  }
}

// ---------------------------------------------------------------------------
// Kernel 1: fused qkv + offsets GEMM.
// x (12544 x 128) @ wt (128 x 776) -> qkv_buf (12544 x 384), off_buf (12544 x 392)
// Block: 32 rows of x staged in LDS (broadcast reads), 256 threads over cols.
// ---------------------------------------------------------------------------
__global__ __launch_bounds__(256) void dwa_gemm_qkv_off(
    const float* __restrict__ x, const float* __restrict__ wt,
    const float* __restrict__ b_qkv, const float* __restrict__ b_off,
    float* __restrict__ qkv_buf, float* __restrict__ off_buf) {
  __shared__ float as[32][128];
  const int m0 = blockIdx.x * 32;
  const int tid = threadIdx.x;
  for (int i = tid; i < 32 * 128; i += 256) {
    as[i >> 7][i & 127] = x[m0 * 128 + i];
  }
  __syncthreads();
  for (int col = tid; col < NCOLS; col += 256) {
    float acc[32];
#pragma unroll
    for (int m = 0; m < 32; ++m) acc[m] = 0.f;
#pragma unroll 2
    for (int k = 0; k < 128; ++k) {
      float wv = wt[k * NCOLS + col];
#pragma unroll
      for (int m = 0; m < 32; ++m) acc[m] = fmaf(as[m][k], wv, acc[m]);
    }
    if (col < 384) {
      float b = b_qkv[col];
      float sc = (col < 128) ? QSCALE : 1.0f;
#pragma unroll
      for (int m = 0; m < 32; ++m) {
        qkv_buf[(m0 + m) * 384 + col] = (acc[m] + b) * sc;
      }
    } else {
      int oc = col - 384;
      float b = b_off[oc];
#pragma unroll
      for (int m = 0; m < 32; ++m) {
        off_buf[(m0 + m) * 392 + oc] = acc[m] + b;
      }
    }
  }
}

// ---------------------------------------------------------------------------
// Kernel 2: deformable window attention, one block per (b, h).
// Stages q/k/v (49x32) in padded LDS; processes n in chunks of 7 rows:
//   phase A: bilinear coords + scores (343 entries)
//   phase B: softmax per row (serial, 7 threads)
//   phase C: PV accumulation (224 threads, one (n,d) each)
// ---------------------------------------------------------------------------
__global__ __launch_bounds__(256) void dwa_attn(
    const float* __restrict__ qkv_buf, const float* __restrict__ off_buf,
    const float* __restrict__ rpb, float* __restrict__ attn_out) {
  const int bh = blockIdx.x;
  const int b = bh >> 2;
  const int h = bh & 3;
  __shared__ float qs[49][33];
  __shared__ float ks[49][33];
  __shared__ float vsh[49][33];
  __shared__ uint32_t idx4[7 * 49];
  __shared__ float wgt[7 * 49][2];
  __shared__ float attn[7][52];
  const int tid = threadIdx.x;

  const float* base = qkv_buf + (size_t)(b * 49) * 384 + h * 32;
  for (int i = tid; i < 49 * 32; i += 256) {
    int n = i >> 5, d = i & 31;
    qs[n][d] = base[n * 384 + d];
    ks[n][d] = base[n * 384 + 128 + d];
    vsh[n][d] = base[n * 384 + 256 + d];
  }
  __syncthreads();

  for (int c = 0; c < 7; ++c) {
    const int n0 = c * 7;
    // ---- phase A: coords + scores ----
    for (int e = tid; e < 7 * 49; e += 256) {
      int r = e / 49;
      int k2 = e - r * 49;
      int n = n0 + r;
      int iy = n / 7, ix = n - iy * 7;
      int tdy = k2 / 7 - 3;
      int tdx = (k2 - (k2 / 7) * 7) - 3;
      const float2 off2 =
          *(const float2*)(off_buf + (size_t)(b * 49 + n) * 392 + h * 98 + k2 * 2);
      float py = (float)(iy + tdy) + off2.x;
      float px = (float)(ix + tdx) + off2.y;
      py = fminf(fmaxf(py, 0.f), 6.f);
      px = fminf(fmaxf(px, 0.f), 6.f);
      float y0f = floorf(py), x0f = floorf(px);
      float wy = py - y0f, wx = px - x0f;
      int y0 = (int)y0f, x0 = (int)x0f;
      int y1 = min(y0 + 1, 6), x1 = min(x0 + 1, 6);
      int i00 = y0 * 7 + x0, i01 = y0 * 7 + x1;
      int i10 = y1 * 7 + x0, i11 = y1 * 7 + x1;
      idx4[e] = (uint32_t)i00 | ((uint32_t)i01 << 8) | ((uint32_t)i10 << 16) |
                ((uint32_t)i11 << 24);
      wgt[e][0] = wy;
      wgt[e][1] = wx;
      float w00 = (1.f - wy) * (1.f - wx);
      float w01 = (1.f - wy) * wx;
      float w10 = wy * (1.f - wx);
      float w11 = wy * wx;
      float s = 0.f;
#pragma unroll 8
      for (int d = 0; d < 32; ++d) {
        float kd = w00 * ks[i00][d] + w01 * ks[i01][d] + w10 * ks[i10][d] +
                   w11 * ks[i11][d];
        s = fmaf(qs[n][d], kd, s);
      }
      s += rpb[h * 169 + (tdy + 6) * 13 + (tdx + 6)];
      attn[r][k2] = s;
    }
    __syncthreads();
    // ---- phase B: softmax (serial per row; 7 rows) ----
    if (tid < 7) {
      int r = tid;
      float mx = -1e30f;
      for (int k2 = 0; k2 < 49; ++k2) mx = fmaxf(mx, attn[r][k2]);
      float sum = 0.f;
      for (int k2 = 0; k2 < 49; ++k2) {
        float e2 = __expf(attn[r][k2] - mx);
        attn[r][k2] = e2;
        sum += e2;
      }
      float inv = 1.f / sum;
      for (int k2 = 0; k2 < 49; ++k2) attn[r][k2] *= inv;
    }
    __syncthreads();
    // ---- phase C: PV ----
    if (tid < 7 * 32) {
      int r = tid >> 5, d = tid & 31;
      int n = n0 + r;
      float acc = 0.f;
      for (int k2 = 0; k2 < 49; ++k2) {
        uint32_t p = idx4[r * 49 + k2];
        float wy = wgt[r * 49 + k2][0];
        float wx = wgt[r * 49 + k2][1];
        float w00 = (1.f - wy) * (1.f - wx);
        float w01 = (1.f - wy) * wx;
        float w10 = wy * (1.f - wx);
        float w11 = wy * wx;
        int i00 = p & 255, i01 = (p >> 8) & 255;
        int i10 = (p >> 16) & 255, i11 = (p >> 24) & 255;
        float vv = w00 * vsh[i00][d] + w01 * vsh[i01][d] + w10 * vsh[i10][d] +
                   w11 * vsh[i11][d];
        acc = fmaf(attn[r][k2], vv, acc);
      }
      attn_out[(size_t)(b * 49 + n) * 128 + h * 32 + d] = acc;
    }
    __syncthreads();
  }
}

// ---------------------------------------------------------------------------
// Kernel 3: proj GEMM. attn_out (12544 x 128) @ wt2 (128 x 128) + b_proj
// Block: 64 rows staged in LDS; 256 threads = (col 0..127) x (half 0..1).
// ---------------------------------------------------------------------------
__global__ __launch_bounds__(256) void dwa_proj(
    const float* __restrict__ attn_out, const float* __restrict__ wt2,
    const float* __restrict__ b_proj, float* __restrict__ out) {
  __shared__ float as[64][128];
  const int m0 = blockIdx.x * 64;
  const int tid = threadIdx.x;
  for (int i = tid; i < 64 * 128; i += 256) {
    as[i >> 7][i & 127] = attn_out[(size_t)m0 * 128 + i];
  }
  __syncthreads();
  const int col = tid & 127;
  const int half = tid >> 7;
  float acc[32];
#pragma unroll
  for (int r = 0; r < 32; ++r) acc[r] = 0.f;
#pragma unroll 2
  for (int k = 0; k < 128; ++k) {
    float wv = wt2[k * 128 + col];
#pragma unroll
    for (int r = 0; r < 32; ++r) acc[r] = fmaf(as[half * 32 + r][k], wv, acc[r]);
  }
  float bp = b_proj[col];
#pragma unroll
  for (int r = 0; r < 32; ++r) {
    out[(size_t)(m0 + half * 32 + r) * 128 + col] = acc[r] + bp;
  }
}

// ---------------------------------------------------------------------------
extern "C" void kernel_launch(void* const* d_in, const int* in_sizes, int n_in,
                              void* d_out, int out_size, void* d_ws,
                              size_t ws_size, hipStream_t stream) {
  const float* x = (const float*)d_in[0];
  const float* w_qkv = (const float*)d_in[1];
  const float* b_qkv = (const float*)d_in[2];
  const float* w_off = (const float*)d_in[3];
  const float* b_off = (const float*)d_in[4];
  const float* rpb = (const float*)d_in[5];
  const float* w_proj = (const float*)d_in[6];
  const float* b_proj = (const float*)d_in[7];
  float* out = (float*)d_out;

  float* ws = (float*)d_ws;
  float* wt = ws;                                  // 128*776   = 99328
  float* wt2 = wt + 128 * NCOLS;                   // 128*128   = 16384
  float* qkv_buf = wt2 + 128 * 128;                // 12544*384 = 4816896
  float* off_buf = qkv_buf + (size_t)MROWS * 384;  // 12544*392 = 4917248
  float* attn_out = off_buf + (size_t)MROWS * 392; // 12544*128 = 1605632

  dwa_transpose_w<<<(128 * NCOLS + 128 * 128 + 255) / 256, 256, 0, stream>>>(
      w_qkv, w_off, w_proj, wt, wt2);
  dwa_gemm_qkv_off<<<MROWS / 32, 256, 0, stream>>>(x, wt, b_qkv, b_off,
                                                   qkv_buf, off_buf);
  dwa_attn<<<BATCH * HEADS, 256, 0, stream>>>(qkv_buf, off_buf, rpb, attn_out);
  dwa_proj<<<MROWS / 64, 256, 0, stream>>>(attn_out, wt2, b_proj, out);
}

// Round 2
// 143.940 us; speedup vs baseline: 2.0315x; 2.0315x over previous
//
#include <hip/hip_runtime.h>
#include <hip/hip_bf16.h>
#include <stdint.h>

// Problem constants
#define BATCH 256
#define NPOS 49
#define CCH 128
#define KWIN 7
#define HEADS 4
#define K2 49
#define HD 32
#define MROWS (BATCH * NPOS)         // 12544
#define QSCALE 0.17677669529663687f  // 32^-0.5

// ---------------------------------------------------------------------------
// Register-tiled fp32 GEMM: C[M x N] = A[M x 128] @ W^T + bias
// MODE 0: A=x, N=832 (13 tiles of 64): cols 0..383 -> qkv_buf (q scaled),
//         cols 384..775 -> off_buf, cols 776..831 discarded.
// MODE 1: A=attn_out, N=128 (2 tiles), W0=w_proj -> out + b_proj.
// Per block: 64x64 tile, 256 threads, 4x4 register tile each.
// LDS: As/Bs both [64][128] with XOR swizzle slot = kq ^ (row&7)  (64 KB).
// ---------------------------------------------------------------------------
template <int MODE>
__global__ __launch_bounds__(256) void dwa_gemm(
    const float* __restrict__ A, const float* __restrict__ W0,
    const float* __restrict__ W1, const float* __restrict__ bias0,
    const float* __restrict__ bias1, float* __restrict__ out0,
    float* __restrict__ out1) {
  __shared__ float As[64][128];
  __shared__ float Bs[64][128];
  const int tid = threadIdx.x;
  const int m0 = blockIdx.x * 64;
  const int n0 = blockIdx.y * 64;

  // ---- stage A (rows m0..m0+63, K=128), swizzled ----
  {
    const float4* src = (const float4*)(A + (size_t)m0 * 128);
#pragma unroll
    for (int p = 0; p < 8; ++p) {
      int i4 = tid + p * 256;
      int m = i4 >> 5;
      int kq = i4 & 31;
      float4 v = src[i4];
      int slot = kq ^ (m & 7);
      *(float4*)&As[m][slot << 2] = v;
    }
  }
  // ---- stage B (cols n0..n0+63 of W, i.e. rows of W0/W1), swizzled ----
  {
#pragma unroll
    for (int p = 0; p < 8; ++p) {
      int i4 = tid + p * 256;
      int c = i4 >> 5;
      int kq = i4 & 31;
      int col = n0 + c;
      float4 v;
      if (MODE == 0) {
        if (col < 384)
          v = *(const float4*)&W0[col * 128 + (kq << 2)];
        else if (col < 776)
          v = *(const float4*)&W1[(col - 384) * 128 + (kq << 2)];
        else
          v = make_float4(0.f, 0.f, 0.f, 0.f);
      } else {
        v = *(const float4*)&W0[col * 128 + (kq << 2)];
      }
      int slot = kq ^ (c & 7);
      *(float4*)&Bs[c][slot << 2] = v;
    }
  }
  __syncthreads();

  const int tx = tid & 15;
  const int ty = tid >> 4;
  // thread cols: c_j = tx + 16*j  (so c_j & 7 == tx & 7 for all j)
  float acc[4][4];
#pragma unroll
  for (int i = 0; i < 4; ++i)
#pragma unroll
    for (int j = 0; j < 4; ++j) acc[i][j] = 0.f;

#pragma unroll 2
  for (int kq = 0; kq < 32; ++kq) {
    float4 a[4];
#pragma unroll
    for (int i = 0; i < 4; ++i) {
      int m = ty * 4 + i;
      a[i] = *(float4*)&As[m][((kq ^ (m & 7)) << 2)];
    }
    int bslot = (kq ^ (tx & 7)) << 2;
    float4 b0 = *(float4*)&Bs[tx][bslot];
    float4 b1 = *(float4*)&Bs[tx + 16][bslot];
    float4 b2 = *(float4*)&Bs[tx + 32][bslot];
    float4 b3 = *(float4*)&Bs[tx + 48][bslot];
#pragma unroll
    for (int i = 0; i < 4; ++i) {
      acc[i][0] = fmaf(a[i].x, b0.x, acc[i][0]);
      acc[i][0] = fmaf(a[i].y, b0.y, acc[i][0]);
      acc[i][0] = fmaf(a[i].z, b0.z, acc[i][0]);
      acc[i][0] = fmaf(a[i].w, b0.w, acc[i][0]);
      acc[i][1] = fmaf(a[i].x, b1.x, acc[i][1]);
      acc[i][1] = fmaf(a[i].y, b1.y, acc[i][1]);
      acc[i][1] = fmaf(a[i].z, b1.z, acc[i][1]);
      acc[i][1] = fmaf(a[i].w, b1.w, acc[i][1]);
      acc[i][2] = fmaf(a[i].x, b2.x, acc[i][2]);
      acc[i][2] = fmaf(a[i].y, b2.y, acc[i][2]);
      acc[i][2] = fmaf(a[i].z, b2.z, acc[i][2]);
      acc[i][2] = fmaf(a[i].w, b2.w, acc[i][2]);
      acc[i][3] = fmaf(a[i].x, b3.x, acc[i][3]);
      acc[i][3] = fmaf(a[i].y, b3.y, acc[i][3]);
      acc[i][3] = fmaf(a[i].z, b3.z, acc[i][3]);
      acc[i][3] = fmaf(a[i].w, b3.w, acc[i][3]);
    }
  }

  // ---- epilogue ----
  if (MODE == 1) {
    float bj[4];
#pragma unroll
    for (int j = 0; j < 4; ++j) bj[j] = bias0[n0 + tx + 16 * j];
#pragma unroll
    for (int i = 0; i < 4; ++i) {
      float* orow = out0 + (size_t)(m0 + ty * 4 + i) * 128;
#pragma unroll
      for (int j = 0; j < 4; ++j) orow[n0 + tx + 16 * j] = acc[i][j] + bj[j];
    }
  } else {
    if (n0 < 384) {
      const float sc = (n0 < 128) ? QSCALE : 1.0f;
      float bj[4];
#pragma unroll
      for (int j = 0; j < 4; ++j) bj[j] = bias0[n0 + tx + 16 * j];
#pragma unroll
      for (int i = 0; i < 4; ++i) {
        float* orow = out0 + (size_t)(m0 + ty * 4 + i) * 384;
#pragma unroll
        for (int j = 0; j < 4; ++j)
          orow[n0 + tx + 16 * j] = (acc[i][j] + bj[j]) * sc;
      }
    } else {
      float bj[4];
      int oc[4];
      bool ok[4];
#pragma unroll
      for (int j = 0; j < 4; ++j) {
        oc[j] = n0 + tx + 16 * j - 384;
        ok[j] = oc[j] < 392;
        bj[j] = ok[j] ? bias1[oc[j]] : 0.f;
      }
#pragma unroll
      for (int i = 0; i < 4; ++i) {
        float* orow = out1 + (size_t)(m0 + ty * 4 + i) * 392;
#pragma unroll
        for (int j = 0; j < 4; ++j)
          if (ok[j]) orow[oc[j]] = acc[i][j] + bj[j];
      }
    }
  }
}

// ---------------------------------------------------------------------------
// Deformable window attention, one block per (b, h), 256 threads.
// Phases: stage q/k/v -> S0 = q@k^T (49x49) -> score assembly via bilinear
// combine of S0 -> row softmax stats -> A2 scatter (attn * bilinear wts)
// -> out = A2 @ v.
// ---------------------------------------------------------------------------
__global__ __launch_bounds__(256) void dwa_attn(
    const float* __restrict__ qkv_buf, const float* __restrict__ off_buf,
    const float* __restrict__ rpb, float* __restrict__ attn_out) {
  __shared__ float qs[49][36];    // q rows (pitch 36, 16B aligned)
  __shared__ float kt[32][68];    // k transposed: kt[d][n]
  __shared__ float vsh[49][36];   // v rows
  __shared__ float S0A2[49][52];  // S0 then reused as A2
  __shared__ float pm[49][52];    // scores -> exp(s - max)
  __shared__ float bias_s[49];
  __shared__ float inv_s[49];

  const int bh = blockIdx.x;
  const int b = bh >> 2;
  const int h = bh & 3;
  const int tid = threadIdx.x;

  // ---- stage ----
  {
    const float* base = qkv_buf + (size_t)(b * 49) * 384 + h * 32;
    for (int i4 = tid; i4 < 392; i4 += 256) {
      int n = i4 >> 3;
      int d4 = (i4 & 7) << 2;
      const float* rowp = base + n * 384 + d4;
      float4 qv = *(const float4*)(rowp);
      float4 kv = *(const float4*)(rowp + 128);
      float4 vv = *(const float4*)(rowp + 256);
      *(float4*)&qs[n][d4] = qv;
      *(float4*)&vsh[n][d4] = vv;
      kt[d4 + 0][n] = kv.x;
      kt[d4 + 1][n] = kv.y;
      kt[d4 + 2][n] = kv.z;
      kt[d4 + 3][n] = kv.w;
    }
    if (tid < 49) {
      int k2 = tid;
      int ky = k2 / 7, kx = k2 - ky * 7;
      bias_s[k2] = rpb[h * 169 + (ky + 3) * 13 + (kx + 3)];
    }
  }
  __syncthreads();

  // ---- S0 = q @ k^T  (49x49, padded compute to 64x64) ----
  {
    const int tx = tid & 15;
    const int ty = tid >> 4;
    int nrow[4];
#pragma unroll
    for (int i = 0; i < 4; ++i) nrow[i] = min(ty * 4 + i, 48);
    float sacc[4][4];
#pragma unroll
    for (int i = 0; i < 4; ++i)
#pragma unroll
      for (int j = 0; j < 4; ++j) sacc[i][j] = 0.f;
#pragma unroll
    for (int kq = 0; kq < 8; ++kq) {
      float4 a[4];
#pragma unroll
      for (int i = 0; i < 4; ++i) a[i] = *(float4*)&qs[nrow[i]][kq << 2];
      float4 bm[4];
#pragma unroll
      for (int u = 0; u < 4; ++u)
        bm[u] = *(float4*)&kt[(kq << 2) + u][tx << 2];
#pragma unroll
      for (int i = 0; i < 4; ++i) {
#pragma unroll
        for (int u = 0; u < 4; ++u) {
          sacc[i][0] = fmaf((&a[i].x)[u], bm[u].x, sacc[i][0]);
          sacc[i][1] = fmaf((&a[i].x)[u], bm[u].y, sacc[i][1]);
          sacc[i][2] = fmaf((&a[i].x)[u], bm[u].z, sacc[i][2]);
          sacc[i][3] = fmaf((&a[i].x)[u], bm[u].w, sacc[i][3]);
        }
      }
    }
    if ((tx << 2) < 49) {  // cols 52..63 never read; row dups benign
#pragma unroll
      for (int i = 0; i < 4; ++i) {
        *(float4*)&S0A2[nrow[i]][tx << 2] =
            make_float4(sacc[i][0], sacc[i][1], sacc[i][2], sacc[i][3]);
      }
    }
  }
  __syncthreads();

  // ---- score assembly: s = sum_c w_c * S0[n][idx_c] + bias ----
  const float* offp = off_buf + (size_t)(b * 49) * 392 + h * 98;
  for (int e = tid; e < 2401; e += 256) {
    unsigned int eu = e;
    int n = eu / 49u;
    int k2 = e - n * 49;
    unsigned int nu = n, ku = k2;
    int iy = nu / 7u, ix = n - iy * 7;
    int ky = ku / 7u, kx = k2 - ky * 7;
    float2 off2 = *(const float2*)(offp + (size_t)n * 392 + k2 * 2);
    float py = (float)(iy + ky - 3) + off2.x;
    float px = (float)(ix + kx - 3) + off2.y;
    py = fminf(fmaxf(py, 0.f), 6.f);
    px = fminf(fmaxf(px, 0.f), 6.f);
    float y0f = floorf(py), x0f = floorf(px);
    float wy = py - y0f, wx = px - x0f;
    int y0 = (int)y0f, x0 = (int)x0f;
    int y1 = min(y0 + 1, 6), x1 = min(x0 + 1, 6);
    int i00 = y0 * 7 + x0, i01 = y0 * 7 + x1;
    int i10 = y1 * 7 + x0, i11 = y1 * 7 + x1;
    float w00 = (1.f - wy) * (1.f - wx);
    float w01 = (1.f - wy) * wx;
    float w10 = wy * (1.f - wx);
    float w11 = wy * wx;
    float s = w00 * S0A2[n][i00] + w01 * S0A2[n][i01] + w10 * S0A2[n][i10] +
              w11 * S0A2[n][i11] + bias_s[k2];
    pm[n][k2] = s;
  }
  __syncthreads();

  // ---- row stats (wave 0) + zero A2 (waves 1..3) ----
  if (tid < 49) {
    int r = tid;
    float mx = -1e30f;
    for (int k2 = 0; k2 < 49; ++k2) mx = fmaxf(mx, pm[r][k2]);
    float sum = 0.f;
    for (int k2 = 0; k2 < 49; ++k2) {
      float e2 = __expf(pm[r][k2] - mx);
      pm[r][k2] = e2;
      sum += e2;
    }
    inv_s[r] = 1.f / sum;
  } else if (tid >= 64) {
    float* a2f = &S0A2[0][0];
    for (int i = tid - 64; i < 49 * 52; i += 192) a2f[i] = 0.f;
  }
  __syncthreads();

  // ---- A2 scatter: A2[n][m] += attn(n,k2) * w_c ----
  for (int e = tid; e < 2401; e += 256) {
    unsigned int eu = e;
    int n = eu / 49u;
    int k2 = e - n * 49;
    unsigned int nu = n, ku = k2;
    int iy = nu / 7u, ix = n - iy * 7;
    int ky = ku / 7u, kx = k2 - ky * 7;
    float2 off2 = *(const float2*)(offp + (size_t)n * 392 + k2 * 2);
    float py = (float)(iy + ky - 3) + off2.x;
    float px = (float)(ix + kx - 3) + off2.y;
    py = fminf(fmaxf(py, 0.f), 6.f);
    px = fminf(fmaxf(px, 0.f), 6.f);
    float y0f = floorf(py), x0f = floorf(px);
    float wy = py - y0f, wx = px - x0f;
    int y0 = (int)y0f, x0 = (int)x0f;
    int y1 = min(y0 + 1, 6), x1 = min(x0 + 1, 6);
    int i00 = y0 * 7 + x0, i01 = y0 * 7 + x1;
    int i10 = y1 * 7 + x0, i11 = y1 * 7 + x1;
    float p = pm[n][k2] * inv_s[n];
    float pw00 = p * (1.f - wy) * (1.f - wx);
    float pw01 = p * (1.f - wy) * wx;
    float pw10 = p * wy * (1.f - wx);
    float pw11 = p * wy * wx;
    atomicAdd(&S0A2[n][i00], pw00);
    atomicAdd(&S0A2[n][i01], pw01);
    atomicAdd(&S0A2[n][i10], pw10);
    atomicAdd(&S0A2[n][i11], pw11);
  }
  __syncthreads();

  // ---- out = A2 @ v ----
  for (int i = tid; i < 1568; i += 256) {
    int n = i >> 5;
    int d = i & 31;
    float acc = 0.f;
#pragma unroll
    for (int m0 = 0; m0 < 48; m0 += 4) {
      float4 a4 = *(float4*)&S0A2[n][m0];
      acc = fmaf(a4.x, vsh[m0 + 0][d], acc);
      acc = fmaf(a4.y, vsh[m0 + 1][d], acc);
      acc = fmaf(a4.z, vsh[m0 + 2][d], acc);
      acc = fmaf(a4.w, vsh[m0 + 3][d], acc);
    }
    acc = fmaf(S0A2[n][48], vsh[48][d], acc);
    attn_out[(size_t)(b * 49 + n) * 128 + h * 32 + d] = acc;
  }
}

// ---------------------------------------------------------------------------
extern "C" void kernel_launch(void* const* d_in, const int* in_sizes, int n_in,
                              void* d_out, int out_size, void* d_ws,
                              size_t ws_size, hipStream_t stream) {
  const float* x = (const float*)d_in[0];
  const float* w_qkv = (const float*)d_in[1];
  const float* b_qkv = (const float*)d_in[2];
  const float* w_off = (const float*)d_in[3];
  const float* b_off = (const float*)d_in[4];
  const float* rpb = (const float*)d_in[5];
  const float* w_proj = (const float*)d_in[6];
  const float* b_proj = (const float*)d_in[7];
  float* out = (float*)d_out;

  float* ws = (float*)d_ws;
  float* qkv_buf = ws;                              // 12544*384
  float* off_buf = qkv_buf + (size_t)MROWS * 384;   // 12544*392
  float* attn_out = off_buf + (size_t)MROWS * 392;  // 12544*128

  dwa_gemm<0><<<dim3(196, 13), 256, 0, stream>>>(x, w_qkv, w_off, b_qkv, b_off,
                                                 qkv_buf, off_buf);
  dwa_attn<<<BATCH * HEADS, 256, 0, stream>>>(qkv_buf, off_buf, rpb, attn_out);
  dwa_gemm<1><<<dim3(196, 2), 256, 0, stream>>>(attn_out, w_proj, nullptr,
                                                b_proj, nullptr, out, nullptr);
}